// Round 22
// baseline (249.324 us; speedup 1.0000x reference)
//
#include <hip/hip_runtime.h>
#include <math.h>

typedef __attribute__((ext_vector_type(8))) short vbf8;
typedef __attribute__((ext_vector_type(4))) short vbf4;
typedef __attribute__((ext_vector_type(4))) float vf4;
typedef __attribute__((ext_vector_type(2))) unsigned int vu2;

__device__ __forceinline__ short f2bf(float f) {
  union { float f; unsigned int u; } v; v.f = f;
  unsigned int r = v.u + 0x7fffu + ((v.u >> 16) & 1u);
  return (short)(r >> 16);
}
__device__ __forceinline__ unsigned int cvtpk(float a, float b) {
  unsigned int r;
  asm("v_cvt_pk_bf16_f32 %0, %1, %2" : "=v"(r) : "v"(a), "v"(b));
  return r;
}
__device__ __forceinline__ float fexp2(float x) {
#if __has_builtin(__builtin_amdgcn_exp2f)
  return __builtin_amdgcn_exp2f(x);
#else
  return exp2f(x);
#endif
}

__device__ __forceinline__ void gload16(const void* g, void* l) {
  __builtin_amdgcn_global_load_lds(
      (const __attribute__((address_space(1))) unsigned int*)g,
      (__attribute__((address_space(3))) unsigned int*)l, 16, 0, 0);
}

// ---------- f32 -> bf16 convert ----------
__global__ __launch_bounds__(256) void cvt_kernel(const float* __restrict__ src,
                                                  short* __restrict__ dst, int n) {
  int i = (blockIdx.x * 256 + threadIdx.x) * 4;
  if (i >= n) return;
  float4 v = *(const float4*)(src + i);
  vu2 o;
  o.x = cvtpk(v.x, v.y);
  o.y = cvtpk(v.z, v.w);
  *(vu2*)(dst + i) = o;
}

// ---------- Wq/Wk/Wv in one launch ----------
__global__ __launch_bounds__(256) void cvtw_kernel(
    const float* __restrict__ Wq, const float* __restrict__ Wk,
    const float* __restrict__ Wv, short* __restrict__ wqkv) {
  const int bid = blockIdx.x;
  const int wsel = bid >> 10;
  const int off = ((bid & 1023) * 256 + threadIdx.x) * 4;
  const float* s = (wsel == 0) ? Wq : (wsel == 1) ? Wk : Wv;
  float4 v = *(const float4*)(s + off);
  vu2 o;
  o.x = cvtpk(v.x, v.y);
  o.y = cvtpk(v.z, v.w);
  *(vu2*)(wqkv + wsel * 1048576 + off) = o;
}

// ---------- GEMM C = A * B^T (128x128 m97 structure) ----------
template <int EPI>
__global__ __launch_bounds__(256) void gemm_bt(
    const short* __restrict__ A, const short* __restrict__ Bw, int K,
    short* __restrict__ qb, short* __restrict__ kb, short* __restrict__ vtb,
    const float* __restrict__ bo, float* __restrict__ outp) {
  __shared__ __align__(16) short As[128 * 32];
  __shared__ __align__(16) short Bs[128 * 32];
  const int lane = threadIdx.x & 63;
  const int w = threadIdx.x >> 6;
  const int wr = w >> 1, wc = w & 1;

  const unsigned flat = blockIdx.y * gridDim.x + blockIdx.x;
  const unsigned cpx = (gridDim.x * gridDim.y) >> 3;
  const unsigned swz = (flat & 7) * cpx + (flat >> 3);
  const int m0 = (int)(swz / gridDim.x) * 128, n0 = (int)(swz % gridDim.x) * 128;

  const short* ga = A + (size_t)(m0 + w * 32 + (lane >> 2)) * K + (lane & 3) * 8;
  const short* gb = Bw + (size_t)(n0 + w * 32 + (lane >> 2)) * K + (lane & 3) * 8;
  short* lA = As + w * 1024;
  short* lB = Bs + w * 1024;

  vf4 acc[4][4];
#pragma unroll
  for (int i = 0; i < 4; ++i)
#pragma unroll
    for (int j = 0; j < 4; ++j) acc[i][j] = (vf4){0.f, 0.f, 0.f, 0.f};

  const int ar = wr * 64 + (lane & 15);
  const int br = wc * 64 + (lane & 15);
  const int kk = (lane >> 4) * 8;

  for (int k0 = 0; k0 < K; k0 += 32) {
    gload16(ga + k0, lA);
    gload16(ga + k0 + 16 * K, lA + 512);
    gload16(gb + k0, lB);
    gload16(gb + k0 + 16 * K, lB + 512);
    __syncthreads();
    vbf8 af[4], bfr[4];
#pragma unroll
    for (int mf = 0; mf < 4; ++mf) af[mf] = *(const vbf8*)(As + (ar + mf * 16) * 32 + kk);
#pragma unroll
    for (int nf = 0; nf < 4; ++nf) bfr[nf] = *(const vbf8*)(Bs + (br + nf * 16) * 32 + kk);
#pragma unroll
    for (int mf = 0; mf < 4; ++mf)
#pragma unroll
      for (int nf = 0; nf < 4; ++nf)
        acc[mf][nf] = __builtin_amdgcn_mfma_f32_16x16x32_bf16(af[mf], bfr[nf], acc[mf][nf], 0, 0, 0);
    __syncthreads();
  }

#pragma unroll
  for (int mf = 0; mf < 4; ++mf) {
    const int mbase = m0 + wr * 64 + mf * 16 + (lane >> 4) * 4;
#pragma unroll
    for (int nf = 0; nf < 4; ++nf) {
      vf4 v = acc[mf][nf];
      const int n = n0 + wc * 64 + nf * 16 + (lane & 15);
      if (EPI == 0) {
        const int region = n >> 10;  // 0=Q 1=K 2=V
        const int nn = n & 1023;
        const int h = nn >> 6, d = nn & 63;
        if (region == 0) {
#pragma unroll
          for (int i = 0; i < 4; ++i) {
            const int m = mbase + i;
            const int b = m >> 11, t = m & 2047;
            qb[((size_t)(b * 16 + h) * 2048 + t) * 64 + d] = f2bf(v[i] * 0.1803368801111204f);
          }
        } else if (region == 1) {
#pragma unroll
          for (int i = 0; i < 4; ++i) {
            const int m = mbase + i;
            const int b = m >> 11, t = m & 2047;
            kb[((size_t)(b * 16 + h) * 2048 + t) * 64 + d] = f2bf(v[i]);
          }
        } else {
          const int b = mbase >> 11, t = mbase & 2047;
          vbf4 o;
          o.x = f2bf(v.x); o.y = f2bf(v.y); o.z = f2bf(v.z); o.w = f2bf(v.w);
          *(vbf4*)(vtb + ((size_t)(b * 16 + h) * 64 + d) * 2048 + t) = o;
        }
      } else {
        const float bias = bo[n];
#pragma unroll
        for (int i = 0; i < 4; ++i) {
          const int m = mbase + i;
          outp[(size_t)m * 1024 + n] = v[i] + bias;
        }
      }
    }
  }
}

// ---------- flash attention: 2-wave blocks, K/V shared via swizzled LDS ----------
// 512 blocks x 128 thr, XCD-affine, balanced strip pairing (34 tiles/wave).
// Block owns a 128-q-row strip; wave w handles rows +w*64 (4 qfi). Per tile
// each wave stages HALF of K+V (8 global_load_lds, pre-swizzled source) into
// double-buffered LDS; swizzled ds_read_b128 fragments (validated 0-conflict
// in gemm256). One vmcnt(0)+barrier per tile; stage(t+1) issued at tile-top.
__global__ __launch_bounds__(128) void attn_kernel(
    const short* __restrict__ Qh, const short* __restrict__ Kh,
    const short* __restrict__ Vt, short* __restrict__ ctx) {
  __shared__ __align__(16) short Ks[2][64 * 64];
  __shared__ __align__(16) short Vs[2][64 * 64];
  __shared__ __align__(16) short Ps[2][16 * 68];

  const int tid = threadIdx.x;
  const int lane = tid & 63;
  const int w = tid >> 6;              // wave 0/1
  const int l15 = lane & 15, g = lane >> 4;
  const int bid = blockIdx.x;
  const int x = bid & 7;
  const int kidx = bid >> 3;           // 0..63 within XCD
  const int p_idx = kidx & 7;
  const int Sp = kidx >> 3;            // 0..7
  const int pair = x + 8 * p_idx;
  const int b = pair >> 4, h = pair & 15;

  const size_t bhoff = (size_t)pair * 131072;
  const short* Qp = Qh + bhoff;
  const short* Kp = Kh + bhoff;
  const short* Vp = Vt + bhoff;
  const int sr = lane >> 3;                    // staging row-in-8 (0..7)
  const int scol = ((lane & 7) ^ sr) * 8;      // pre-swizzled source col (shorts)
  short* Pw = Ps[w];

  auto runStrip = [&](int S) {
    const int wq0 = S * 128 + w * 64;
    const int nt = 2 * S + 2;

    vbf8 qfr[4][2];
#pragma unroll
    for (int qfi = 0; qfi < 4; ++qfi)
#pragma unroll
      for (int ks = 0; ks < 2; ++ks)
        qfr[qfi][ks] = *(const vbf8*)(Qp + (size_t)(wq0 + qfi * 16 + l15) * 64 +
                                      ks * 32 + g * 8);

    vf4 o2[4][4];
    float mrow[4], lrow[4];
#pragma unroll
    for (int qfi = 0; qfi < 4; ++qfi) {
#pragma unroll
      for (int df = 0; df < 4; ++df) o2[qfi][df] = (vf4){0.f, 0.f, 0.f, 0.f};
      mrow[qfi] = -1e30f; lrow[qfi] = 0.f;
    }

    // wave w stages K rows [w*32, w*32+32) and V^T rows [w*32, w*32+32)
    auto stage = [&](int tt, int bb) {
      const int k0s = tt * 64;
#pragma unroll
      for (int j = 0; j < 4; ++j)
        gload16(Kp + (size_t)(k0s + w * 32 + j * 8 + sr) * 64 + scol,
                &Ks[bb][(w * 32 + j * 8) * 64]);
#pragma unroll
      for (int j = 0; j < 4; ++j)
        gload16(Vp + (size_t)(w * 32 + j * 8 + sr) * 2048 + k0s + scol,
                &Vs[bb][(w * 32 + j * 8) * 64]);
    };

    stage(0, 0);
    asm volatile("s_waitcnt vmcnt(0)" ::: "memory");
    __builtin_amdgcn_s_barrier();

    for (int t = 0; t < nt; ++t) {
      const int bb = t & 1;
      if (t + 1 < nt) stage(t + 1, bb ^ 1);  // buf^1 retired at t-1's barrier

      if (t <= 2 * S + w) {                  // wave-uniform compute guard
        const int k0 = t * 64;
#pragma unroll
        for (int qfi = 0; qfi < 4; ++qfi) {
          const int q = wq0 + qfi * 16 + l15;
          const bool needmask = (k0 + 64 > wq0 + qfi * 16);

          vf4 s[4];
          __builtin_amdgcn_s_setprio(1);
#pragma unroll
          for (int kf = 0; kf < 4; ++kf) {
            s[kf] = (vf4){0.f, 0.f, 0.f, 0.f};
#pragma unroll
            for (int ks = 0; ks < 2; ++ks) {
              const vbf8 kfrag = *(const vbf8*)(&Ks[bb][(kf * 16 + l15) * 64 +
                                                        ((ks * 4 + g) ^ (l15 & 7)) * 8]);
              s[kf] = __builtin_amdgcn_mfma_f32_16x16x32_bf16(kfrag, qfr[qfi][ks],
                                                              s[kf], 0, 0, 0);
            }
          }
          __builtin_amdgcn_s_setprio(0);

          if (needmask) {
#pragma unroll
            for (int kf = 0; kf < 4; ++kf) {
              const int kbase = k0 + kf * 16 + g * 4;
#pragma unroll
              for (int i = 0; i < 4; ++i)
                if (kbase + i > q) s[kf][i] = -1e30f;
            }
          }
          float t0 = fmaxf(fmaxf(s[0][0], s[0][1]), fmaxf(s[0][2], s[0][3]));
          float t1 = fmaxf(fmaxf(s[1][0], s[1][1]), fmaxf(s[1][2], s[1][3]));
          float t2 = fmaxf(fmaxf(s[2][0], s[2][1]), fmaxf(s[2][2], s[2][3]));
          float t3 = fmaxf(fmaxf(s[3][0], s[3][1]), fmaxf(s[3][2], s[3][3]));
          const float mxl = fmaxf(fmaxf(t0, t1), fmaxf(t2, t3));

          float mn = mrow[qfi];
          if (!__all((int)(mxl - mn <= 8.f))) {
            float mx = fmaxf(mxl, __shfl_xor(mxl, 16));
            mx = fmaxf(mx, __shfl_xor(mx, 32));
            mn = fmaxf(mrow[qfi], mx);
            const float al = fexp2(mrow[qfi] - mn);
            mrow[qfi] = mn;
            lrow[qfi] *= al;
#pragma unroll
            for (int df = 0; df < 4; ++df)
#pragma unroll
              for (int i = 0; i < 4; ++i) o2[qfi][df][i] *= al;
          }

          float rs = 0.f;
#pragma unroll
          for (int kf = 0; kf < 4; ++kf)
#pragma unroll
            for (int i = 0; i < 4; ++i) {
              const float p = fexp2(s[kf][i] - mn);
              s[kf][i] = p;
              rs += p;
            }
          lrow[qfi] += rs;

#pragma unroll
          for (int kf = 0; kf < 4; ++kf) {
            vu2 pk;
            pk.x = cvtpk(s[kf][0], s[kf][1]);
            pk.y = cvtpk(s[kf][2], s[kf][3]);
            *(vu2*)(Pw + l15 * 68 + kf * 16 + g * 4) = pk;
          }

          vbf8 pb[2];
#pragma unroll
          for (int ks2 = 0; ks2 < 2; ++ks2)
            pb[ks2] = *(const vbf8*)(Pw + l15 * 68 + ks2 * 32 + g * 8);

          __builtin_amdgcn_s_setprio(1);
#pragma unroll
          for (int ks2 = 0; ks2 < 2; ++ks2)
#pragma unroll
            for (int df = 0; df < 4; ++df) {
              const vbf8 vfrag = *(const vbf8*)(&Vs[bb][(df * 16 + l15) * 64 +
                                                        ((ks2 * 4 + g) ^ (l15 & 7)) * 8]);
              o2[qfi][df] = __builtin_amdgcn_mfma_f32_16x16x32_bf16(vfrag, pb[ks2],
                                                                    o2[qfi][df], 0, 0, 0);
            }
          __builtin_amdgcn_s_setprio(0);
        }
      }

      // drain this wave's stage(t+1) then sync: barrier doubles as
      // "loads landed" + "everyone done reading buf bb"
      asm volatile("s_waitcnt vmcnt(0)" ::: "memory");
      __builtin_amdgcn_s_barrier();
    }

    // epilogue
#pragma unroll
    for (int qfi = 0; qfi < 4; ++qfi) {
      float lsum = lrow[qfi];
      lsum += __shfl_xor(lsum, 16);
      lsum += __shfl_xor(lsum, 32);
      const float inv = 1.f / lsum;
      const int q = wq0 + qfi * 16 + l15;
      short* dst = ctx + (size_t)(b * 2048 + q) * 1024 + h * 64;
#pragma unroll
      for (int df = 0; df < 4; ++df) {
        vu2 o;
        o.x = cvtpk(o2[qfi][df][0] * inv, o2[qfi][df][1] * inv);
        o.y = cvtpk(o2[qfi][df][2] * inv, o2[qfi][df][3] * inv);
        *(vu2*)(dst + df * 16 + g * 4) = o;
      }
    }
  };

  runStrip(15 - Sp);  // heavy strip: 32-2*Sp tiles
  runStrip(Sp);       // light strip: 2*Sp+2 tiles -> 34 per wave
}

extern "C" void kernel_launch(void* const* d_in, const int* in_sizes, int n_in,
                              void* d_out, int out_size, void* d_ws, size_t ws_size,
                              hipStream_t stream) {
  const float* x  = (const float*)d_in[0];
  const float* Wq = (const float*)d_in[1];
  const float* Wk = (const float*)d_in[2];
  const float* Wv = (const float*)d_in[3];
  const float* Wo = (const float*)d_in[4];
  const float* bo = (const float*)d_in[5];
  float* out = (float*)d_out;

  char* ws = (char*)d_ws;
  short* xb   = (short*)(ws);                  // 16 MB, reused as ctx later
  short* wqkv = (short*)(ws + 16777216);       // 6 MB, reused as Wo bf16 later
  short* qb   = (short*)(ws + 23068672);       // 16 MB
  short* kb   = (short*)(ws + 39845888);       // 16 MB
  short* vtb  = (short*)(ws + 56623104);       // 16 MB  (V transposed [B,H,64,T])
  short* ctxb = xb;
  short* wob  = wqkv;                          // safe: wqkv dead after gemm_bt<0>

  cvt_kernel<<<8192, 256, 0, stream>>>(x, xb, 8388608);
  cvtw_kernel<<<3072, 256, 0, stream>>>(Wq, Wk, Wv, wqkv);
  gemm_bt<0><<<dim3(24, 64), 256, 0, stream>>>(xb, wqkv, 1024, qb, kb, vtb, nullptr, nullptr);
  cvt_kernel<<<1024, 256, 0, stream>>>(Wo, wob, 1048576);
  attn_kernel<<<512, 128, 0, stream>>>(qb, kb, vtb, ctxb);
  gemm_bt<1><<<dim3(8, 64), 256, 0, stream>>>(ctxb, wob, 1024, nullptr, nullptr, nullptr, bo, out);
}

// Round 23
// 204.828 us; speedup vs baseline: 1.2172x; 1.2172x over previous
//
#include <hip/hip_runtime.h>
#include <math.h>

typedef __attribute__((ext_vector_type(8))) short vbf8;
typedef __attribute__((ext_vector_type(4))) short vbf4;
typedef __attribute__((ext_vector_type(4))) float vf4;
typedef __attribute__((ext_vector_type(2))) unsigned int vu2;

__device__ __forceinline__ short f2bf(float f) {
  union { float f; unsigned int u; } v; v.f = f;
  unsigned int r = v.u + 0x7fffu + ((v.u >> 16) & 1u);
  return (short)(r >> 16);
}
__device__ __forceinline__ unsigned int cvtpk(float a, float b) {
  unsigned int r;
  asm("v_cvt_pk_bf16_f32 %0, %1, %2" : "=v"(r) : "v"(a), "v"(b));
  return r;
}
__device__ __forceinline__ float fexp2(float x) {
#if __has_builtin(__builtin_amdgcn_exp2f)
  return __builtin_amdgcn_exp2f(x);
#else
  return exp2f(x);
#endif
}

__device__ __forceinline__ void gload16(const void* g, void* l) {
  __builtin_amdgcn_global_load_lds(
      (const __attribute__((address_space(1))) unsigned int*)g,
      (__attribute__((address_space(3))) unsigned int*)l, 16, 0, 0);
}

// ---------- f32 -> bf16 convert ----------
__global__ __launch_bounds__(256) void cvt_kernel(const float* __restrict__ src,
                                                  short* __restrict__ dst, int n) {
  int i = (blockIdx.x * 256 + threadIdx.x) * 4;
  if (i >= n) return;
  float4 v = *(const float4*)(src + i);
  vu2 o;
  o.x = cvtpk(v.x, v.y);
  o.y = cvtpk(v.z, v.w);
  *(vu2*)(dst + i) = o;
}

// ---------- Wq/Wk/Wv in one launch ----------
__global__ __launch_bounds__(256) void cvtw_kernel(
    const float* __restrict__ Wq, const float* __restrict__ Wk,
    const float* __restrict__ Wv, short* __restrict__ wqkv) {
  const int bid = blockIdx.x;
  const int wsel = bid >> 10;
  const int off = ((bid & 1023) * 256 + threadIdx.x) * 4;
  const float* s = (wsel == 0) ? Wq : (wsel == 1) ? Wk : Wv;
  float4 v = *(const float4*)(s + off);
  vu2 o;
  o.x = cvtpk(v.x, v.y);
  o.y = cvtpk(v.z, v.w);
  *(vu2*)(wqkv + wsel * 1048576 + off) = o;
}

// ---------- GEMM C = A * B^T (128x128 m97 structure) ----------
template <int EPI>
__global__ __launch_bounds__(256) void gemm_bt(
    const short* __restrict__ A, const short* __restrict__ Bw, int K,
    short* __restrict__ qb, short* __restrict__ kb, short* __restrict__ vtb,
    const float* __restrict__ bo, float* __restrict__ outp) {
  __shared__ __align__(16) short As[128 * 32];
  __shared__ __align__(16) short Bs[128 * 32];
  const int lane = threadIdx.x & 63;
  const int w = threadIdx.x >> 6;
  const int wr = w >> 1, wc = w & 1;

  const unsigned flat = blockIdx.y * gridDim.x + blockIdx.x;
  const unsigned cpx = (gridDim.x * gridDim.y) >> 3;
  const unsigned swz = (flat & 7) * cpx + (flat >> 3);
  const int m0 = (int)(swz / gridDim.x) * 128, n0 = (int)(swz % gridDim.x) * 128;

  const short* ga = A + (size_t)(m0 + w * 32 + (lane >> 2)) * K + (lane & 3) * 8;
  const short* gb = Bw + (size_t)(n0 + w * 32 + (lane >> 2)) * K + (lane & 3) * 8;
  short* lA = As + w * 1024;
  short* lB = Bs + w * 1024;

  vf4 acc[4][4];
#pragma unroll
  for (int i = 0; i < 4; ++i)
#pragma unroll
    for (int j = 0; j < 4; ++j) acc[i][j] = (vf4){0.f, 0.f, 0.f, 0.f};

  const int ar = wr * 64 + (lane & 15);
  const int br = wc * 64 + (lane & 15);
  const int kk = (lane >> 4) * 8;

  for (int k0 = 0; k0 < K; k0 += 32) {
    gload16(ga + k0, lA);
    gload16(ga + k0 + 16 * K, lA + 512);
    gload16(gb + k0, lB);
    gload16(gb + k0 + 16 * K, lB + 512);
    __syncthreads();
    vbf8 af[4], bfr[4];
#pragma unroll
    for (int mf = 0; mf < 4; ++mf) af[mf] = *(const vbf8*)(As + (ar + mf * 16) * 32 + kk);
#pragma unroll
    for (int nf = 0; nf < 4; ++nf) bfr[nf] = *(const vbf8*)(Bs + (br + nf * 16) * 32 + kk);
#pragma unroll
    for (int mf = 0; mf < 4; ++mf)
#pragma unroll
      for (int nf = 0; nf < 4; ++nf)
        acc[mf][nf] = __builtin_amdgcn_mfma_f32_16x16x32_bf16(af[mf], bfr[nf], acc[mf][nf], 0, 0, 0);
    __syncthreads();
  }

#pragma unroll
  for (int mf = 0; mf < 4; ++mf) {
    const int mbase = m0 + wr * 64 + mf * 16 + (lane >> 4) * 4;
#pragma unroll
    for (int nf = 0; nf < 4; ++nf) {
      vf4 v = acc[mf][nf];
      const int n = n0 + wc * 64 + nf * 16 + (lane & 15);
      if (EPI == 0) {
        const int region = n >> 10;  // 0=Q 1=K 2=V
        const int nn = n & 1023;
        const int h = nn >> 6, d = nn & 63;
        if (region == 0) {
#pragma unroll
          for (int i = 0; i < 4; ++i) {
            const int m = mbase + i;
            const int b = m >> 11, t = m & 2047;
            qb[((size_t)(b * 16 + h) * 2048 + t) * 64 + d] = f2bf(v[i] * 0.1803368801111204f);
          }
        } else if (region == 1) {
#pragma unroll
          for (int i = 0; i < 4; ++i) {
            const int m = mbase + i;
            const int b = m >> 11, t = m & 2047;
            kb[((size_t)(b * 16 + h) * 2048 + t) * 64 + d] = f2bf(v[i]);
          }
        } else {
          const int b = mbase >> 11, t = mbase & 2047;
          vbf4 o;
          o.x = f2bf(v.x); o.y = f2bf(v.y); o.z = f2bf(v.z); o.w = f2bf(v.w);
          *(vbf4*)(vtb + ((size_t)(b * 16 + h) * 64 + d) * 2048 + t) = o;
        }
      } else {
        const float bias = bo[n];
#pragma unroll
        for (int i = 0; i < 4; ++i) {
          const int m = mbase + i;
          outp[(size_t)m * 1024 + n] = v[i] + bias;
        }
      }
    }
  }
}

// ---------- flash attention, causal, swapped-operand, BALANCED pairing ----------
// 1024 single-wave blocks, XCD-affine. Block (x, p_idx, Wp) runs strip
// W=31-Wp (heavy) then W=Wp (light): every wave does exactly 33 KV-tiles.
__global__ __launch_bounds__(64) void attn_kernel(
    const short* __restrict__ Qh, const short* __restrict__ Kh,
    const short* __restrict__ Vt, short* __restrict__ ctx) {
  __shared__ __align__(16) short Ps[16 * 68];

  const int lane = threadIdx.x;
  const int l15 = lane & 15, g = lane >> 4;
  const int bid = blockIdx.x;
  const int x = bid & 7;
  const int kidx = bid >> 3;           // 0..127 within XCD
  const int p_idx = kidx & 7;
  const int Wp = kidx >> 3;            // 0..15
  const int pair = x + 8 * p_idx;
  const int b = pair >> 4, h = pair & 15;

  const size_t bhoff = (size_t)pair * 131072;
  const short* Qp = Qh + bhoff;
  const short* Kp = Kh + bhoff;
  const short* Vp = Vt + bhoff;

  auto runStrip = [&](int W) {
    const int wq0 = W * 64;

    vbf8 qfr[4][2];
#pragma unroll
    for (int qfi = 0; qfi < 4; ++qfi)
#pragma unroll
      for (int ks = 0; ks < 2; ++ks)
        qfr[qfi][ks] = *(const vbf8*)(Qp + (size_t)(wq0 + qfi * 16 + l15) * 64 +
                                      ks * 32 + g * 8);

    vf4 o2[4][4];
    float mrow[4], lrow[4];
#pragma unroll
    for (int qfi = 0; qfi < 4; ++qfi) {
#pragma unroll
      for (int df = 0; df < 4; ++df) o2[qfi][df] = (vf4){0.f, 0.f, 0.f, 0.f};
      mrow[qfi] = -1e30f; lrow[qfi] = 0.f;
    }

    const int nt = W + 1;

    vbf8 kA[4][2], kB[4][2];
    vbf8 vA[2][4], vB[2][4];
    auto loadK = [&](int tt, vbf8 (&kd)[4][2]) {
      const int kb0 = tt * 64;
#pragma unroll
      for (int kf = 0; kf < 4; ++kf)
#pragma unroll
        for (int ks = 0; ks < 2; ++ks)
          kd[kf][ks] = *(const vbf8*)(Kp + (size_t)(kb0 + kf * 16 + l15) * 64 +
                                      ks * 32 + g * 8);
    };
    auto loadV = [&](int tt, vbf8 (&vd)[2][4]) {
      const int k0 = tt * 64;
#pragma unroll
      for (int ks2 = 0; ks2 < 2; ++ks2)
#pragma unroll
        for (int df = 0; df < 4; ++df)
          vd[ks2][df] = *(const vbf8*)(Vp + (size_t)(df * 16 + l15) * 2048 +
                                       k0 + ks2 * 32 + g * 8);
    };
    loadK(0, kA);
    loadV(0, vA);

    auto tile = [&](int t, vbf8 (&kc)[4][2], vbf8 (&kn)[4][2],
                    vbf8 (&vc)[2][4], vbf8 (&vn)[2][4]) {
      const int k0 = t * 64;

      if (t + 1 < nt) {
        loadK(t + 1, kn);
        loadV(t + 1, vn);
      }

#pragma unroll
      for (int qfi = 0; qfi < 4; ++qfi) {
        const int q = wq0 + qfi * 16 + l15;
        const bool needmask = (k0 + 64 > wq0 + qfi * 16);

        vf4 s[4];
        __builtin_amdgcn_s_setprio(1);
#pragma unroll
        for (int kf = 0; kf < 4; ++kf) {
          s[kf] = (vf4){0.f, 0.f, 0.f, 0.f};
#pragma unroll
          for (int ks = 0; ks < 2; ++ks)
            s[kf] = __builtin_amdgcn_mfma_f32_16x16x32_bf16(kc[kf][ks], qfr[qfi][ks],
                                                            s[kf], 0, 0, 0);
        }
        __builtin_amdgcn_s_setprio(0);

        if (needmask) {
#pragma unroll
          for (int kf = 0; kf < 4; ++kf) {
            const int kbase = k0 + kf * 16 + g * 4;
#pragma unroll
            for (int i = 0; i < 4; ++i)
              if (kbase + i > q) s[kf][i] = -1e30f;
          }
        }
        float t0 = fmaxf(fmaxf(s[0][0], s[0][1]), fmaxf(s[0][2], s[0][3]));
        float t1 = fmaxf(fmaxf(s[1][0], s[1][1]), fmaxf(s[1][2], s[1][3]));
        float t2 = fmaxf(fmaxf(s[2][0], s[2][1]), fmaxf(s[2][2], s[2][3]));
        float t3 = fmaxf(fmaxf(s[3][0], s[3][1]), fmaxf(s[3][2], s[3][3]));
        const float mxl = fmaxf(fmaxf(t0, t1), fmaxf(t2, t3));

        float mn = mrow[qfi];
        if (!__all((int)(mxl - mn <= 8.f))) {
          float mx = fmaxf(mxl, __shfl_xor(mxl, 16));
          mx = fmaxf(mx, __shfl_xor(mx, 32));
          mn = fmaxf(mrow[qfi], mx);
          const float al = fexp2(mrow[qfi] - mn);
          mrow[qfi] = mn;
          lrow[qfi] *= al;
#pragma unroll
          for (int df = 0; df < 4; ++df)
#pragma unroll
            for (int i = 0; i < 4; ++i) o2[qfi][df][i] *= al;
        }

        float rs = 0.f;
#pragma unroll
        for (int kf = 0; kf < 4; ++kf)
#pragma unroll
          for (int i = 0; i < 4; ++i) {
            const float p = fexp2(s[kf][i] - mn);
            s[kf][i] = p;
            rs += p;
          }
        lrow[qfi] += rs;

#pragma unroll
        for (int kf = 0; kf < 4; ++kf) {
          vu2 pk;
          pk.x = cvtpk(s[kf][0], s[kf][1]);
          pk.y = cvtpk(s[kf][2], s[kf][3]);
          *(vu2*)(Ps + l15 * 68 + kf * 16 + g * 4) = pk;
        }

        vbf8 pb[2];
#pragma unroll
        for (int ks2 = 0; ks2 < 2; ++ks2)
          pb[ks2] = *(const vbf8*)(Ps + l15 * 68 + ks2 * 32 + g * 8);

        __builtin_amdgcn_s_setprio(1);
#pragma unroll
        for (int ks2 = 0; ks2 < 2; ++ks2)
#pragma unroll
          for (int df = 0; df < 4; ++df)
            o2[qfi][df] = __builtin_amdgcn_mfma_f32_16x16x32_bf16(vc[ks2][df], pb[ks2],
                                                                  o2[qfi][df], 0, 0, 0);
        __builtin_amdgcn_s_setprio(0);
      }
    };

    for (int t = 0; t < nt; t += 2) {
      tile(t, kA, kB, vA, vB);
      if (t + 1 < nt) tile(t + 1, kB, kA, vB, vA);
    }

#pragma unroll
    for (int qfi = 0; qfi < 4; ++qfi) {
      float lsum = lrow[qfi];
      lsum += __shfl_xor(lsum, 16);
      lsum += __shfl_xor(lsum, 32);
      const float inv = 1.f / lsum;
      const int q = wq0 + qfi * 16 + l15;
      short* dst = ctx + (size_t)(b * 2048 + q) * 1024 + h * 64;
#pragma unroll
      for (int df = 0; df < 4; ++df) {
        vu2 o;
        o.x = cvtpk(o2[qfi][df][0] * inv, o2[qfi][df][1] * inv);
        o.y = cvtpk(o2[qfi][df][2] * inv, o2[qfi][df][3] * inv);
        *(vu2*)(dst + df * 16 + g * 4) = o;
      }
    }
  };

  runStrip(31 - Wp);  // heavy strip: 32-Wp tiles
  runStrip(Wp);       // light strip: Wp+1 tiles  -> total 33 per wave
}

extern "C" void kernel_launch(void* const* d_in, const int* in_sizes, int n_in,
                              void* d_out, int out_size, void* d_ws, size_t ws_size,
                              hipStream_t stream) {
  const float* x  = (const float*)d_in[0];
  const float* Wq = (const float*)d_in[1];
  const float* Wk = (const float*)d_in[2];
  const float* Wv = (const float*)d_in[3];
  const float* Wo = (const float*)d_in[4];
  const float* bo = (const float*)d_in[5];
  float* out = (float*)d_out;

  char* ws = (char*)d_ws;
  short* xb   = (short*)(ws);                  // 16 MB, reused as ctx later
  short* wqkv = (short*)(ws + 16777216);       // 6 MB, reused as Wo bf16 later
  short* qb   = (short*)(ws + 23068672);       // 16 MB
  short* kb   = (short*)(ws + 39845888);       // 16 MB
  short* vtb  = (short*)(ws + 56623104);       // 16 MB  (V transposed [B,H,64,T])
  short* ctxb = xb;
  short* wob  = wqkv;                          // safe: wqkv dead after gemm_bt<0>

  cvt_kernel<<<8192, 256, 0, stream>>>(x, xb, 8388608);
  cvtw_kernel<<<3072, 256, 0, stream>>>(Wq, Wk, Wv, wqkv);
  gemm_bt<0><<<dim3(24, 64), 256, 0, stream>>>(xb, wqkv, 1024, qb, kb, vtb, nullptr, nullptr);
  cvt_kernel<<<1024, 256, 0, stream>>>(Wo, wob, 1048576);
  attn_kernel<<<1024, 64, 0, stream>>>(qb, kb, vtb, ctxb);
  gemm_bt<1><<<dim3(8, 64), 256, 0, stream>>>(ctxb, wob, 1024, nullptr, nullptr, nullptr, bo, out);
}